// Round 10
// baseline (488.376 us; speedup 1.0000x reference)
//
#include <hip/hip_runtime.h>
#include <stdint.h>

// Problem constants (from reference setup_inputs): B,H,T,S,D
#define B_ 2
#define H_ 16
#define T_ 2048
#define S_ 2048
#define D_ 128
#define BH_ (B_ * H_)              // 32
#define NKS (S_ / 32)              // 64 k-slots of 32 per bh
#define VKS_B 4096                 // 4 KB per (bh,ks) fp8 V tile
#define NSLAB 32                   // slabs of BK=64 floats (2 k-slots each)

typedef float f32x4 __attribute__((ext_vector_type(4)));

// ---------------------------------------------------------------------------
// Kernel 0: clear the two amax slots (replaces hipMemsetAsync in the graph)
__global__ void init_kernel(unsigned* __restrict__ amax_bits) {
  if (threadIdx.x < 2) amax_bits[threadIdx.x] = 0u;
}

// ---------------------------------------------------------------------------
// Kernel 1: abs-max of A and V in one dispatch (blocks <2048 -> A, rest -> V)
__global__ void amax2_kernel(const float* __restrict__ a, long n4a,
                             const float* __restrict__ v, long n4v,
                             unsigned* __restrict__ out) {
  const f32x4* x4;
  long n4, i, stride;
  unsigned* dst;
  if (blockIdx.x < 2048) {
    x4 = (const f32x4*)a;  n4 = n4a;  dst = out;
    i = (long)blockIdx.x * blockDim.x + threadIdx.x;
    stride = 2048L * blockDim.x;
  } else {
    x4 = (const f32x4*)v;  n4 = n4v;  dst = out + 1;
    i = (long)(blockIdx.x - 2048) * blockDim.x + threadIdx.x;
    stride = 256L * blockDim.x;
  }
  float m = 0.0f;
  for (; i < n4; i += stride) {
    f32x4 val = x4[i];
    m = fmaxf(m, fmaxf(fmaxf(fabsf(val[0]), fabsf(val[1])),
                       fmaxf(fabsf(val[2]), fabsf(val[3]))));
  }
  #pragma unroll
  for (int off = 32; off; off >>= 1) m = fmaxf(m, __shfl_xor(m, off, 64));
  if ((threadIdx.x & 63) == 0) atomicMax(dst, __float_as_uint(m));
}

// ---------------------------------------------------------------------------
// HW e4m3fn quantization helpers (v_cvt_pk_fp8_f32 is RNE, OCP on gfx950).
__device__ __forceinline__ float clamp448(float y) {
  return fminf(fmaxf(y, -448.0f), 448.0f);
}

__device__ __forceinline__ unsigned pack_fp8x4(float a, float b, float c,
                                               float d) {
  int w = 0;
  w = __builtin_amdgcn_cvt_pk_fp8_f32(a, b, w, false);
  w = __builtin_amdgcn_cvt_pk_fp8_f32(c, d, w, true);
  return (unsigned)w;
}

__device__ __forceinline__ long pack_fp8x8(const float* f) {
  unsigned d0 = pack_fp8x4(f[0], f[1], f[2], f[3]);
  unsigned d1 = pack_fp8x4(f[4], f[5], f[6], f[7]);
  return (long)(((unsigned long long)d1 << 32) | d0);
}

__device__ __forceinline__ long mk64(unsigned lo, unsigned hi) {
  return (long)(((unsigned long long)hi << 32) | lo);
}

// async global->LDS, 16B/lane; lptr is the WAVE-UNIFORM base (HW adds
// lane*16), gptr is per-lane [guide §5, m97/m104].
__device__ __forceinline__ void gload_lds16(const void* g, void* l) {
  __builtin_amdgcn_global_load_lds(
      (const __attribute__((address_space(1))) unsigned int*)g,
      (__attribute__((address_space(3))) unsigned int*)l, 16, 0, 0);
}

// ---------------------------------------------------------------------------
// Kernel 2: quantize V -> Vq[bh][ks][i][lane][16B]  (i-major, matches the
// GEMM's B-LDS layout byte-for-byte).  Content per (lane,i): fragments
// ni=2i,2i+1 for (kg=lane>>4, lr=lane&15):
//   byte j of half q = q8( V[bh][ks*32 + kg*8 + j][ (2i+q)*16 + lr ] )
__global__ void quantv_ldsorder_kernel(const float* __restrict__ V,
                                       unsigned char* __restrict__ Vq,
                                       const unsigned* __restrict__ amax_bits) {
  float amax = fmaxf(__uint_as_float(amax_bits[1]), 1e-12f);
  float inv  = 448.0f / amax;
  int bh = blockIdx.x >> 6;          // grid = 32*64
  int ks = blockIdx.x & 63;
  const float*   vb = V  + ((size_t)bh * S_ + (size_t)ks * 32) * D_;
  unsigned char* ob = Vq + ((size_t)bh * NKS + ks) * VKS_B;
  int lane = threadIdx.x & 63;
  int p    = threadIdx.x >> 6;       // 0..3 = i (also the wave id)
  int kg   = lane >> 4;
  int lr   = lane & 15;
  unsigned dw[4];
  #pragma unroll
  for (int q = 0; q < 2; ++q) {      // ni = 2p + q
    int d = (2 * p + q) * 16 + lr;
    float f[8];
    #pragma unroll
    for (int j = 0; j < 8; ++j)
      f[j] = clamp448(vb[(size_t)(kg * 8 + j) * D_ + d] * inv);
    dw[q * 2 + 0] = pack_fp8x4(f[0], f[1], f[2], f[3]);
    dw[q * 2 + 1] = pack_fp8x4(f[4], f[5], f[6], f[7]);
  }
  *(uint4*)(ob + p * 1024 + lane * 16) = *(const uint4*)dw;   // wave-dense 1KB
}

// ---------------------------------------------------------------------------
// Kernel 3a (DIAGNOSTIC v2, runs first; output overwritten by 3b): R8's
// ping-pong register GEMM, B-address adapted to the ldsorder Vq layout
// (same bytes per lane: i*1024 + lane*16 instead of lane*64 + i*16).
// Its duration = R10_total - 340 us.
__global__ __launch_bounds__(256, 1)
void gemm_fused_pp_kernel(const float* __restrict__ A,
                          const unsigned char* __restrict__ Vq,
                          float* __restrict__ out,
                          const unsigned* __restrict__ amax_bits) {
  float amax_a = fmaxf(__uint_as_float(amax_bits[0]), 1e-12f);
  float amax_v = fmaxf(__uint_as_float(amax_bits[1]), 1e-12f);
  float inv_a  = 448.0f / amax_a;
  float out_scale = (amax_a / 448.0f) * (amax_v / 448.0f);

  int bid = blockIdx.x;                      // 1024 blocks, 1024%8==0
  int swz = (bid & 7) * 128 + (bid >> 3);    // XCD-contiguous chunks (T1)
  int bh  = swz >> 5;
  int t0  = (swz & 31) * 64;

  int w    = threadIdx.x >> 6;               // wave 0..3 -> rows [t0+16w,+16)
  int lane = threadIdx.x & 63;
  int lr   = lane & 15;                      // A row-in-frag / B col / C col
  int kg   = lane >> 4;                      // k-group (k = kg*8 + j)

  const float* arow =
      A + (size_t)bh * T_ * S_ + (size_t)(t0 + w * 16 + lr) * S_ + kg * 8;
  const unsigned char* vpanel = Vq + (size_t)bh * NKS * VKS_B;
  const unsigned char* vlane  = vpanel + (size_t)lane * 16;

  f32x4 acc[8];
  #pragma unroll
  for (int j = 0; j < 8; ++j) acc[j] = (f32x4)0.0f;

  // ping-pong sets
  f32x4 A0p0, A1p0, A0p1, A1p1;
  uint4 B0[4], B1[4];

  // prologue: ks=0 -> P0, ks=1 -> P1
  A0p0 = *(const f32x4*)(arow);
  A1p0 = *(const f32x4*)(arow + 4);
  #pragma unroll
  for (int i = 0; i < 4; ++i)
    B0[i] = *(const uint4*)(vlane + i * 1024);
  A0p1 = *(const f32x4*)(arow + 32);
  A1p1 = *(const f32x4*)(arow + 36);
  #pragma unroll
  for (int i = 0; i < 4; ++i)
    B1[i] = *(const uint4*)(vlane + VKS_B + i * 1024);

  #define QUANT_MFMA(A0r, A1r, Br)                                        \
    {                                                                     \
      float f[8];                                                         \
      _Pragma("unroll") for (int j = 0; j < 4; ++j) {                     \
        f[j]     = clamp448((A0r)[j] * inv_a);                            \
        f[j + 4] = clamp448((A1r)[j] * inv_a);                            \
      }                                                                   \
      long afrag = pack_fp8x8(f);                                         \
      _Pragma("unroll") for (int i = 0; i < 4; ++i) {                     \
        acc[2 * i] = __builtin_amdgcn_mfma_f32_16x16x32_fp8_fp8(          \
            afrag, mk64((Br)[i].x, (Br)[i].y), acc[2 * i], 0, 0, 0);      \
        acc[2 * i + 1] = __builtin_amdgcn_mfma_f32_16x16x32_fp8_fp8(      \
            afrag, mk64((Br)[i].z, (Br)[i].w), acc[2 * i + 1], 0, 0, 0);  \
      }                                                                   \
    }

  for (int ks = 0; ks < NKS - 2; ks += 2) {
    QUANT_MFMA(A0p0, A1p0, B0);
    A0p0 = *(const f32x4*)(arow + (size_t)(ks + 2) * 32);
    A1p0 = *(const f32x4*)(arow + (size_t)(ks + 2) * 32 + 4);
    #pragma unroll
    for (int i = 0; i < 4; ++i)
      B0[i] = *(const uint4*)(vlane + (size_t)(ks + 2) * VKS_B + i * 1024);
    QUANT_MFMA(A0p1, A1p1, B1);
    A0p1 = *(const f32x4*)(arow + (size_t)(ks + 3) * 32);
    A1p1 = *(const f32x4*)(arow + (size_t)(ks + 3) * 32 + 4);
    #pragma unroll
    for (int i = 0; i < 4; ++i)
      B1[i] = *(const uint4*)(vlane + (size_t)(ks + 3) * VKS_B + i * 1024);
  }
  QUANT_MFMA(A0p0, A1p0, B0);
  QUANT_MFMA(A0p1, A1p1, B1);
  #undef QUANT_MFMA

  int b = bh >> 4, h = bh & 15;
  float* ob = out + (size_t)b * T_ * (H_ * D_) + (size_t)h * D_;
  int trow = t0 + w * 16;
  #pragma unroll
  for (int ni = 0; ni < 8; ++ni) {
    int d = ni * 16 + lr;
    #pragma unroll
    for (int r = 0; r < 4; ++r) {
      int t = trow + kg * 4 + r;
      ob[(size_t)t * (H_ * D_) + d] = acc[ni][r] * out_scale;
    }
  }
}

// ---------------------------------------------------------------------------
// Kernel 3b: R9's global_load_lds 2-phase GEMM (unchanged; final output).
__global__ __launch_bounds__(256, 3)
void gemm_lds_kernel(const float* __restrict__ A,
                     const unsigned char* __restrict__ Vq,
                     float* __restrict__ out,
                     const unsigned* __restrict__ amax_bits) {
  __shared__ __align__(16) unsigned char sA[2][16384];   // [buf][row][256B]
  __shared__ __align__(16) unsigned char sB[2][8192];    // [buf][ks][i][l][16]

  float amax_a = fmaxf(__uint_as_float(amax_bits[0]), 1e-12f);
  float amax_v = fmaxf(__uint_as_float(amax_bits[1]), 1e-12f);
  float inv_a  = 448.0f / amax_a;
  float out_scale = (amax_a / 448.0f) * (amax_v / 448.0f);

  int bid = blockIdx.x;                      // 1024 blocks, 1024%8==0
  int swz = (bid & 7) * 128 + (bid >> 3);    // XCD-contiguous chunks (T1)
  int bh  = swz >> 5;
  int t0  = (swz & 31) * 64;

  int w    = threadIdx.x >> 6;               // wave 0..3 -> rows [t0+16w,+16)
  int lane = threadIdx.x & 63;
  int lr   = lane & 15;                      // A row-in-frag / B col / C col
  int kg   = lane >> 4;                      // k-group (k = kg*8 + j)
  int swzA = (lr & 7) << 4;                  // read-side XOR (lane-constant)

  const char* abase = (const char*)A + (size_t)bh * T_ * S_ * 4;
  const unsigned char* vpanel = Vq + (size_t)bh * NKS * VKS_B;

  f32x4 acc[8];
  #pragma unroll
  for (int j = 0; j < 8; ++j) acc[j] = (f32x4)0.0f;

  auto stageA = [&](int buf, int s) {
    #pragma unroll
    for (int i = 0; i < 4; ++i) {
      int row_local = i * 4 + (lane >> 4);             // 0..15
      int grow = t0 + w * 16 + row_local;
      const char* src = abase + ((size_t)grow * S_ + (size_t)s * 64) * 4 +
                        (((lane & 15) * 16) ^ ((row_local & 7) << 4));
      gload_lds16(src, &sA[buf][w * 4096 + i * 1024]);
    }
  };
  auto stageB = [&](int buf, int s) {
    const unsigned char* vt = vpanel + (size_t)(s * 2) * VKS_B;
    #pragma unroll
    for (int j = 0; j < 2; ++j)
      gload_lds16(vt + w * 2048 + j * 1024 + lane * 16,
                  &sB[buf][w * 2048 + j * 1024]);
  };
  auto compute = [&](int buf) {
    #pragma unroll
    for (int ks = 0; ks < 2; ++ks) {
      const unsigned char* ab = &sA[buf][w * 4096 + lr * 256];
      f32x4 x0 = *(const f32x4*)(ab + ((ks * 128 + kg * 32) ^ swzA));
      f32x4 x1 = *(const f32x4*)(ab + ((ks * 128 + kg * 32 + 16) ^ swzA));
      float f[8];
      #pragma unroll
      for (int j = 0; j < 4; ++j) {
        f[j]     = clamp448(x0[j] * inv_a);
        f[j + 4] = clamp448(x1[j] * inv_a);
      }
      long afrag = pack_fp8x8(f);
      const unsigned char* bb = &sB[buf][ks * 4096 + lane * 16];
      #pragma unroll
      for (int i = 0; i < 4; ++i) {
        uint4 bv = *(const uint4*)(bb + i * 1024);
        acc[2 * i] = __builtin_amdgcn_mfma_f32_16x16x32_fp8_fp8(
            afrag, mk64(bv.x, bv.y), acc[2 * i], 0, 0, 0);
        acc[2 * i + 1] = __builtin_amdgcn_mfma_f32_16x16x32_fp8_fp8(
            afrag, mk64(bv.z, bv.w), acc[2 * i + 1], 0, 0, 0);
      }
    }
  };

  stageA(0, 0);
  stageB(0, 0);
  __syncthreads();
  int buf = 0;
  for (int t = 0; t < NSLAB; ++t) {
    if (t + 1 < NSLAB) {
      stageA(buf ^ 1, t + 1);
      stageB(buf ^ 1, t + 1);
    }
    compute(buf);
    __syncthreads();
    buf ^= 1;
  }

  int b = bh >> 4, h = bh & 15;
  float* ob = out + (size_t)b * T_ * (H_ * D_) + (size_t)h * D_;
  int trow = t0 + w * 16;
  #pragma unroll
  for (int ni = 0; ni < 8; ++ni) {
    int d = ni * 16 + lr;
    #pragma unroll
    for (int r = 0; r < 4; ++r) {
      int t = trow + kg * 4 + r;
      ob[(size_t)t * (H_ * D_) + d] = acc[ni][r] * out_scale;
    }
  }
}

// ---------------------------------------------------------------------------
// Fallback (tiny d_ws): fused in-register quant GEMM, f32 A + f32 V direct.
__global__ __launch_bounds__(256, 4)
void gemm_fused_kernel(const float* __restrict__ A,
                       const float* __restrict__ Vf, float* __restrict__ out,
                       const unsigned* __restrict__ amax_bits) {
  float amax_a = fmaxf(__uint_as_float(amax_bits[0]), 1e-12f);
  float amax_v = fmaxf(__uint_as_float(amax_bits[1]), 1e-12f);
  float inv_a  = 448.0f / amax_a;
  float inv_v  = 448.0f / amax_v;
  float out_scale = (amax_a / 448.0f) * (amax_v / 448.0f);

  int bid  = blockIdx.x;
  int bh   = bid >> 5;
  int t0   = (bid & 31) * 64;
  int b    = bh >> 4;
  int h    = bh & 15;
  int wave = threadIdx.x >> 6;
  int lane = threadIdx.x & 63;
  int lr   = lane & 15;
  int kg   = lane >> 4;

  const float* arow =
      A + (size_t)bh * T_ * S_ + (size_t)(t0 + wave * 16 + lr) * S_;
  const float* vfb = Vf + (size_t)bh * S_ * D_;

  f32x4 acc[8];
  #pragma unroll
  for (int j = 0; j < 8; ++j) acc[j] = (f32x4)0.0f;

  for (int ks = 0; ks < S_ / 32; ++ks) {
    int kb = ks * 32 + kg * 8;
    long bfrag[8];
    #pragma unroll
    for (int ni = 0; ni < 8; ++ni) {
      float f[8];
      #pragma unroll
      for (int j = 0; j < 8; ++j)
        f[j] = clamp448(vfb[(size_t)(kb + j) * D_ + ni * 16 + lr] * inv_v);
      bfrag[ni] = pack_fp8x8(f);
    }
    f32x4 x0 = *(const f32x4*)(arow + kb);
    f32x4 x1 = *(const f32x4*)(arow + kb + 4);
    float f[8];
    #pragma unroll
    for (int j = 0; j < 4; ++j) {
      f[j]     = clamp448(x0[j] * inv_a);
      f[j + 4] = clamp448(x1[j] * inv_a);
    }
    long afrag = pack_fp8x8(f);
    #pragma unroll
    for (int ni = 0; ni < 8; ++ni)
      acc[ni] = __builtin_amdgcn_mfma_f32_16x16x32_fp8_fp8(afrag, bfrag[ni],
                                                           acc[ni], 0, 0, 0);
  }

  float* ob = out + (size_t)b * T_ * H_ * D_ + (size_t)h * D_;
  int trow = t0 + wave * 16;
  #pragma unroll
  for (int ni = 0; ni < 8; ++ni) {
    int d = ni * 16 + lr;
    #pragma unroll
    for (int r = 0; r < 4; ++r) {
      int t = trow + kg * 4 + r;
      ob[(size_t)t * H_ * D_ + d] = acc[ni][r] * out_scale;
    }
  }
}

// ---------------------------------------------------------------------------
extern "C" void kernel_launch(void* const* d_in, const int* in_sizes, int n_in,
                              void* d_out, int out_size, void* d_ws, size_t ws_size,
                              hipStream_t stream) {
  const float* aw = (const float*)d_in[0];
  const float* v  = (const float*)d_in[1];
  float* out      = (float*)d_out;

  unsigned*      amax_bits = (unsigned*)d_ws;
  unsigned char* vq        = (unsigned char*)d_ws + 256;
  size_t vq_bytes = (size_t)BH_ * NKS * VKS_B;            // 8 MB
  size_t need_full = 256 + vq_bytes;

  init_kernel<<<1, 64, 0, stream>>>(amax_bits);

  long n4a = (long)B_ * H_ * T_ * S_ / 4;
  long n4v = (long)B_ * H_ * S_ * D_ / 4;
  amax2_kernel<<<2304, 256, 0, stream>>>(aw, n4a, v, n4v, amax_bits);

  if (ws_size >= need_full) {
    quantv_ldsorder_kernel<<<BH_ * NKS, 256, 0, stream>>>(v, vq, amax_bits);
    // DIAGNOSTIC dispatch: duration = total - 340us. Output overwritten below.
    gemm_fused_pp_kernel<<<BH_ * 32, 256, 0, stream>>>(aw, vq, out,
                                                       amax_bits);
    gemm_lds_kernel<<<BH_ * 32, 256, 0, stream>>>(aw, vq, out, amax_bits);
  } else {
    gemm_fused_kernel<<<B_ * H_ * (T_ / 64), 256, 0, stream>>>(aw, v, out,
                                                               amax_bits);
  }
}

// Round 11
// 316.394 us; speedup vs baseline: 1.5436x; 1.5436x over previous
//
#include <hip/hip_runtime.h>
#include <stdint.h>

// Problem constants (from reference setup_inputs): B,H,T,S,D
#define B_ 2
#define H_ 16
#define T_ 2048
#define S_ 2048
#define D_ 128
#define BH_ (B_ * H_)              // 32
#define NKS (S_ / 32)              // 64 k-slots of 32 per bh
#define VKS_B 4096                 // 4 KB per (bh,ks) fp8 V tile
#define NSLAB 32                   // slabs of BK=64 floats (2 k-slots each)
#define AROW_B 72                  // padded LDS stride for fp8 A rows (64+8)

typedef float f32x4 __attribute__((ext_vector_type(4)));

// ---------------------------------------------------------------------------
// Kernel 0: clear the two amax slots (replaces hipMemsetAsync in the graph)
__global__ void init_kernel(unsigned* __restrict__ amax_bits) {
  if (threadIdx.x < 2) amax_bits[threadIdx.x] = 0u;
}

// ---------------------------------------------------------------------------
// Kernel 1: abs-max of A and V in one dispatch (blocks <2048 -> A, rest -> V)
__global__ void amax2_kernel(const float* __restrict__ a, long n4a,
                             const float* __restrict__ v, long n4v,
                             unsigned* __restrict__ out) {
  const f32x4* x4;
  long n4, i, stride;
  unsigned* dst;
  if (blockIdx.x < 2048) {
    x4 = (const f32x4*)a;  n4 = n4a;  dst = out;
    i = (long)blockIdx.x * blockDim.x + threadIdx.x;
    stride = 2048L * blockDim.x;
  } else {
    x4 = (const f32x4*)v;  n4 = n4v;  dst = out + 1;
    i = (long)(blockIdx.x - 2048) * blockDim.x + threadIdx.x;
    stride = 256L * blockDim.x;
  }
  float m = 0.0f;
  for (; i < n4; i += stride) {
    f32x4 val = x4[i];
    m = fmaxf(m, fmaxf(fmaxf(fabsf(val[0]), fabsf(val[1])),
                       fmaxf(fabsf(val[2]), fabsf(val[3]))));
  }
  #pragma unroll
  for (int off = 32; off; off >>= 1) m = fmaxf(m, __shfl_xor(m, off, 64));
  if ((threadIdx.x & 63) == 0) atomicMax(dst, __float_as_uint(m));
}

// ---------------------------------------------------------------------------
// HW e4m3fn quantization helpers (v_cvt_pk_fp8_f32 is RNE, OCP on gfx950).
__device__ __forceinline__ float clamp448(float y) {
  return fminf(fmaxf(y, -448.0f), 448.0f);
}

__device__ __forceinline__ unsigned pack_fp8x4(float a, float b, float c,
                                               float d) {
  int w = 0;
  w = __builtin_amdgcn_cvt_pk_fp8_f32(a, b, w, false);
  w = __builtin_amdgcn_cvt_pk_fp8_f32(c, d, w, true);
  return (unsigned)w;
}

__device__ __forceinline__ long pack_fp8x8(const float* f) {
  unsigned d0 = pack_fp8x4(f[0], f[1], f[2], f[3]);
  unsigned d1 = pack_fp8x4(f[4], f[5], f[6], f[7]);
  return (long)(((unsigned long long)d1 << 32) | d0);
}

__device__ __forceinline__ long mk64(unsigned lo, unsigned hi) {
  return (long)(((unsigned long long)hi << 32) | lo);
}

// async global->LDS, 16B/lane; lptr is the WAVE-UNIFORM base (HW adds
// lane*16), gptr is per-lane [guide §5, m97/m104].
__device__ __forceinline__ void gload_lds16(const void* g, void* l) {
  __builtin_amdgcn_global_load_lds(
      (const __attribute__((address_space(1))) unsigned int*)g,
      (__attribute__((address_space(3))) unsigned int*)l, 16, 0, 0);
}

// ---------------------------------------------------------------------------
// Kernel 2: quantize V -> Vq[bh][ks][i][lane][16B]  (i-major, matches the
// GEMM's B-LDS layout byte-for-byte).  Content per (lane,i): fragments
// ni=2i,2i+1 for (kg=lane>>4, lr=lane&15):
//   byte j of half q = q8( V[bh][ks*32 + kg*8 + j][ (2i+q)*16 + lr ] )
__global__ void quantv_ldsorder_kernel(const float* __restrict__ V,
                                       unsigned char* __restrict__ Vq,
                                       const unsigned* __restrict__ amax_bits) {
  float amax = fmaxf(__uint_as_float(amax_bits[1]), 1e-12f);
  float inv  = 448.0f / amax;
  int bh = blockIdx.x >> 6;          // grid = 32*64
  int ks = blockIdx.x & 63;
  const float*   vb = V  + ((size_t)bh * S_ + (size_t)ks * 32) * D_;
  unsigned char* ob = Vq + ((size_t)bh * NKS + ks) * VKS_B;
  int lane = threadIdx.x & 63;
  int p    = threadIdx.x >> 6;       // 0..3 = i (also the wave id)
  int kg   = lane >> 4;
  int lr   = lane & 15;
  unsigned dw[4];
  #pragma unroll
  for (int q = 0; q < 2; ++q) {      // ni = 2p + q
    int d = (2 * p + q) * 16 + lr;
    float f[8];
    #pragma unroll
    for (int j = 0; j < 8; ++j)
      f[j] = clamp448(vb[(size_t)(kg * 8 + j) * D_ + d] * inv);
    dw[q * 2 + 0] = pack_fp8x4(f[0], f[1], f[2], f[3]);
    dw[q * 2 + 1] = pack_fp8x4(f[4], f[5], f[6], f[7]);
  }
  *(uint4*)(ob + p * 1024 + lane * 16) = *(const uint4*)dw;   // wave-dense 1KB
}

// ---------------------------------------------------------------------------
// Kernel 3: fused quant+GEMM, reg-staged A (T14) + gload_lds B.
//  - block = 4 waves, 64x128 C-tile; wave owns 16 rows.
//  - per slab (BK=64 floats): A staged DENSE (4x dwordx4/wave, no source
//    permutation), quantized to fp8 in regs, ds_write into padded LDS
//    [16 rows][AROW_B]: write = 2 lanes/bank (free), ds_read_b64 frag = 4-cyc
//    structural floor (addr/4 = 18*lr+8*ks+2*kg covers banks uniformly).
//  - B staged via gload_lds (dense 1-KB), shared by the block's 4 waves.
//  - order per iter: issue A-loads(t+1) + B-stage(t+1) -> compute(t) ->
//    quant+ds_write(t+1) -> barrier.  Load latency hides under compute.
//  - LDS 25.6 KB; launch_bounds(256,4) caps VGPR at 128 (est ~90, no spill).
__global__ __launch_bounds__(256, 4)
void gemm_regA_kernel(const float* __restrict__ A,
                      const unsigned char* __restrict__ Vq,
                      float* __restrict__ out,
                      const unsigned* __restrict__ amax_bits) {
  __shared__ __align__(16) unsigned char sAq[2][4][16 * AROW_B];  // 9216 B
  __shared__ __align__(16) unsigned char sB[2][8192];             // 16384 B

  float amax_a = fmaxf(__uint_as_float(amax_bits[0]), 1e-12f);
  float amax_v = fmaxf(__uint_as_float(amax_bits[1]), 1e-12f);
  float inv_a  = 448.0f / amax_a;
  float out_scale = (amax_a / 448.0f) * (amax_v / 448.0f);

  int bid = blockIdx.x;                      // 1024 blocks, 1024%8==0
  int swz = (bid & 7) * 128 + (bid >> 3);    // XCD-contiguous chunks (T1)
  int bh  = swz >> 5;
  int t0  = (swz & 31) * 64;

  int w    = threadIdx.x >> 6;               // wave 0..3 -> rows [t0+16w,+16)
  int lane = threadIdx.x & 63;
  int lr   = lane & 15;                      // A row-in-frag / B col / C col
  int kg   = lane >> 4;                      // k-group (k = kg*8 + j)
  int srow = (lane >> 4);                    // stage row-in-4 (0..3)
  int scol = (lane & 15) * 4;                // stage float col (0..60)

  const float* abase =
      A + (size_t)bh * T_ * S_ + (size_t)(t0 + w * 16) * S_;
  const unsigned char* vpanel = Vq + (size_t)bh * NKS * VKS_B;

  f32x4 acc[8];
  #pragma unroll
  for (int j = 0; j < 8; ++j) acc[j] = (f32x4)0.0f;

  f32x4 rA[4];

  // dense A loads: instr i covers rows 4i..4i+3, 256 B contiguous per row
  auto loadA = [&](int t) {
    #pragma unroll
    for (int i = 0; i < 4; ++i)
      rA[i] = *(const f32x4*)(abase + (size_t)(i * 4 + srow) * S_ +
                              (size_t)t * 64 + scol);
  };
  auto stageB = [&](int buf, int t) {
    const unsigned char* vt = vpanel + (size_t)(t * 2) * VKS_B;
    #pragma unroll
    for (int j = 0; j < 2; ++j)
      gload_lds16(vt + w * 2048 + j * 1024 + lane * 16,
                  &sB[buf][w * 2048 + j * 1024]);
  };
  // quantize rA -> fp8, write 4 B/lane/row into padded [row][AROW_B] tile
  auto quantWrite = [&](int buf) {
    unsigned char* aw_ = &sAq[buf][w][0];
    #pragma unroll
    for (int i = 0; i < 4; ++i) {
      unsigned q4 = pack_fp8x4(
          clamp448(rA[i][0] * inv_a), clamp448(rA[i][1] * inv_a),
          clamp448(rA[i][2] * inv_a), clamp448(rA[i][3] * inv_a));
      *(unsigned*)(aw_ + (i * 4 + srow) * AROW_B + scol) = q4;
    }
  };
  auto compute = [&](int buf) {
    const unsigned char* ar = &sAq[buf][w][0];
    #pragma unroll
    for (int ks = 0; ks < 2; ++ks) {
      long afrag = *(const long*)(ar + lr * AROW_B + ks * 32 + kg * 8);
      const unsigned char* bb = &sB[buf][ks * 4096 + lane * 16];
      #pragma unroll
      for (int i = 0; i < 4; ++i) {
        uint4 bv = *(const uint4*)(bb + i * 1024);
        acc[2 * i] = __builtin_amdgcn_mfma_f32_16x16x32_fp8_fp8(
            afrag, mk64(bv.x, bv.y), acc[2 * i], 0, 0, 0);
        acc[2 * i + 1] = __builtin_amdgcn_mfma_f32_16x16x32_fp8_fp8(
            afrag, mk64(bv.z, bv.w), acc[2 * i + 1], 0, 0, 0);
      }
    }
  };

  // prologue: slab 0
  loadA(0);
  stageB(0, 0);
  quantWrite(0);
  __syncthreads();
  int buf = 0;
  for (int t = 0; t < NSLAB; ++t) {
    if (t + 1 < NSLAB) {
      loadA(t + 1);                 // issue early: hides under compute (T14)
      stageB(buf ^ 1, t + 1);
    }
    compute(buf);
    if (t + 1 < NSLAB) quantWrite(buf ^ 1);
    __syncthreads();
    buf ^= 1;
  }

  // ---- epilogue: C/D layout col=lane&15, row=(lane>>4)*4+r  [guide §3, m89]
  // out[b][t][h][d], d = ni*16+lr, t = t0 + w*16 + kg*4 + r
  int b = bh >> 4, h = bh & 15;
  float* ob = out + (size_t)b * T_ * (H_ * D_) + (size_t)h * D_;
  int trow = t0 + w * 16;
  #pragma unroll
  for (int ni = 0; ni < 8; ++ni) {
    int d = ni * 16 + lr;
    #pragma unroll
    for (int r = 0; r < 4; ++r) {
      int t = trow + kg * 4 + r;
      ob[(size_t)t * (H_ * D_) + d] = acc[ni][r] * out_scale;
    }
  }
}

// ---------------------------------------------------------------------------
// Fallback (tiny d_ws): fused in-register quant GEMM, f32 A + f32 V direct.
__global__ __launch_bounds__(256, 4)
void gemm_fused_kernel(const float* __restrict__ A,
                       const float* __restrict__ Vf, float* __restrict__ out,
                       const unsigned* __restrict__ amax_bits) {
  float amax_a = fmaxf(__uint_as_float(amax_bits[0]), 1e-12f);
  float amax_v = fmaxf(__uint_as_float(amax_bits[1]), 1e-12f);
  float inv_a  = 448.0f / amax_a;
  float inv_v  = 448.0f / amax_v;
  float out_scale = (amax_a / 448.0f) * (amax_v / 448.0f);

  int bid  = blockIdx.x;
  int bh   = bid >> 5;
  int t0   = (bid & 31) * 64;
  int b    = bh >> 4;
  int h    = bh & 15;
  int wave = threadIdx.x >> 6;
  int lane = threadIdx.x & 63;
  int lr   = lane & 15;
  int kg   = lane >> 4;

  const float* arow =
      A + (size_t)bh * T_ * S_ + (size_t)(t0 + wave * 16 + lr) * S_;
  const float* vfb = Vf + (size_t)bh * S_ * D_;

  f32x4 acc[8];
  #pragma unroll
  for (int j = 0; j < 8; ++j) acc[j] = (f32x4)0.0f;

  for (int ks = 0; ks < S_ / 32; ++ks) {
    int kb = ks * 32 + kg * 8;
    long bfrag[8];
    #pragma unroll
    for (int ni = 0; ni < 8; ++ni) {
      float f[8];
      #pragma unroll
      for (int j = 0; j < 8; ++j)
        f[j] = clamp448(vfb[(size_t)(kb + j) * D_ + ni * 16 + lr] * inv_v);
      bfrag[ni] = pack_fp8x8(f);
    }
    f32x4 x0 = *(const f32x4*)(arow + kb);
    f32x4 x1 = *(const f32x4*)(arow + kb + 4);
    float f[8];
    #pragma unroll
    for (int j = 0; j < 4; ++j) {
      f[j]     = clamp448(x0[j] * inv_a);
      f[j + 4] = clamp448(x1[j] * inv_a);
    }
    long afrag = pack_fp8x8(f);
    #pragma unroll
    for (int ni = 0; ni < 8; ++ni)
      acc[ni] = __builtin_amdgcn_mfma_f32_16x16x32_fp8_fp8(afrag, bfrag[ni],
                                                           acc[ni], 0, 0, 0);
  }

  float* ob = out + (size_t)b * T_ * H_ * D_ + (size_t)h * D_;
  int trow = t0 + wave * 16;
  #pragma unroll
  for (int ni = 0; ni < 8; ++ni) {
    int d = ni * 16 + lr;
    #pragma unroll
    for (int r = 0; r < 4; ++r) {
      int t = trow + kg * 4 + r;
      ob[(size_t)t * H_ * D_ + d] = acc[ni][r] * out_scale;
    }
  }
}

// ---------------------------------------------------------------------------
extern "C" void kernel_launch(void* const* d_in, const int* in_sizes, int n_in,
                              void* d_out, int out_size, void* d_ws, size_t ws_size,
                              hipStream_t stream) {
  const float* aw = (const float*)d_in[0];
  const float* v  = (const float*)d_in[1];
  float* out      = (float*)d_out;

  unsigned*      amax_bits = (unsigned*)d_ws;
  unsigned char* vq        = (unsigned char*)d_ws + 256;
  size_t vq_bytes = (size_t)BH_ * NKS * VKS_B;            // 8 MB
  size_t need_full = 256 + vq_bytes;

  init_kernel<<<1, 64, 0, stream>>>(amax_bits);

  long n4a = (long)B_ * H_ * T_ * S_ / 4;
  long n4v = (long)B_ * H_ * S_ * D_ / 4;
  amax2_kernel<<<2304, 256, 0, stream>>>(aw, n4a, v, n4v, amax_bits);

  if (ws_size >= need_full) {
    quantv_ldsorder_kernel<<<BH_ * NKS, 256, 0, stream>>>(v, vq, amax_bits);
    gemm_regA_kernel<<<BH_ * 32, 256, 0, stream>>>(aw, vq, out, amax_bits);
  } else {
    gemm_fused_kernel<<<B_ * H_ * (T_ / 64), 256, 0, stream>>>(aw, v, out,
                                                               amax_bits);
  }
}